// Round 2
// baseline (68.500 us; speedup 1.0000x reference)
//
#include <hip/hip_runtime.h>

#define NN 8
#define CC 3
#define HH 64
#define WW 64
#define OO 64

__global__ __launch_bounds__(256) void sconv2d_kernel(
    const float* __restrict__ x,      // (N, C, H, W)
    const float* __restrict__ wt,     // (O, C, 3, 3) -> flat (O, 27)
    const float* __restrict__ bias,   // (O,)
    float* __restrict__ out)          // (N, O, H, W)
{
    const int w  = threadIdx.x & 63;        // 0..63
    const int hi = threadIdx.x >> 6;        // 0..3
    const int h  = (blockIdx.x << 2) + hi;  // 0..63
    const int o  = blockIdx.y;              // 0..63
    const int n  = blockIdx.z;              // 0..7

    // 27 weights for this output channel (block-uniform address -> cache broadcast)
    float wreg[27];
    #pragma unroll
    for (int i = 0; i < 27; ++i) wreg[i] = wt[o * 27 + i];

    // products v[l], l = c*9 + dh*3 + dw   (matches reference stacking order)
    float v[27];
    #pragma unroll
    for (int c = 0; c < CC; ++c) {
        const float* __restrict__ xc = x + ((n * CC + c) * HH) * WW;
        #pragma unroll
        for (int dh = 0; dh < 3; ++dh) {
            const int hh = h + dh - 1;
            const bool hok = (hh >= 0) & (hh < HH);
            #pragma unroll
            for (int dw = 0; dw < 3; ++dw) {
                const int ww = w + dw - 1;
                const bool ok = hok & (ww >= 0) & (ww < WW);
                const float xv = ok ? xc[hh * WW + ww] : 0.0f;
                v[c * 9 + dh * 3 + dw] = xv * wreg[c * 9 + dh * 3 + dw];
            }
        }
    }

    // ternary tree reduce 27 -> 9 -> 3 -> 1, consecutive triples, reference FP order:
    // (a + b + c - a*b*c) * 0.5
    #pragma unroll
    for (int L = 27; L > 1; L /= 3) {
        #pragma unroll
        for (int i = 0; i < L / 3; ++i) {
            const float a = v[3 * i + 0];
            const float b = v[3 * i + 1];
            const float cc = v[3 * i + 2];
            v[i] = (a + b + cc - a * b * cc) * 0.5f;
        }
    }

    out[((n * OO + o) * HH + h) * WW + w] = v[0] + bias[o];
}

extern "C" void kernel_launch(void* const* d_in, const int* in_sizes, int n_in,
                              void* d_out, int out_size, void* d_ws, size_t ws_size,
                              hipStream_t stream) {
    const float* x    = (const float*)d_in[0];
    const float* wt   = (const float*)d_in[1];
    const float* bias = (const float*)d_in[2];
    float* out        = (float*)d_out;

    dim3 grid(HH / 4, OO, NN);   // 16 x 64 x 8 = 8192 blocks
    sconv2d_kernel<<<grid, 256, 0, stream>>>(x, wt, bias, out);
}

// Round 3
// 66.286 us; speedup vs baseline: 1.0334x; 1.0334x over previous
//
#include <hip/hip_runtime.h>

#define NN 8
#define CC 3
#define HH 64
#define WW 64
#define OO 64

__device__ __forceinline__ float f3(float a, float b, float c) {
    // reference: (a + b + c - a*b*c) * 0.5  (left-assoc adds)
    return (a + b + c - a * b * c) * 0.5f;
}

__global__ __launch_bounds__(256) void sconv2d_kernel(
    const float* __restrict__ x,      // (N, C, H, W)
    const float* __restrict__ wt,     // (O, C, 3, 3) flat (O, 27)
    const float* __restrict__ bias,   // (O,)
    float* __restrict__ out)          // (N, O, H, W)
{
    const int lane16 = threadIdx.x & 15;
    const int w0 = lane16 << 2;                         // 0,4,...,60 (aligned)
    const int h  = (blockIdx.x << 4) + (threadIdx.x >> 4); // 0..63
    const int o0 = blockIdx.y << 1;                     // 2 output channels/block
    const int n  = blockIdx.z;

    // 54 block-uniform weights -> scalar loads (SGPR-resident)
    float wgt[2][27];
    #pragma unroll
    for (int q = 0; q < 2; ++q)
        #pragma unroll
        for (int i = 0; i < 27; ++i)
            wgt[q][i] = wt[(o0 + q) * 27 + i];

    float u[3][2][4];   // [c][o][pixel] level-2 partials

    #pragma unroll
    for (int c = 0; c < CC; ++c) {
        const float* __restrict__ xc = x + ((n * CC + c) * HH) * WW;
        // stage 3 rows x 6 cols (cols w0-1 .. w0+4) in registers
        float xr[3][6];
        #pragma unroll
        for (int dh = 0; dh < 3; ++dh) {
            const int hh = h + dh - 1;
            const bool hok = (hh >= 0) && (hh < HH);
            const float* rowp = xc + hh * WW;
            if (hok) {
                // center 4 cols always in-bounds, aligned float4
                const float4 mid = *reinterpret_cast<const float4*>(rowp + w0);
                xr[dh][1] = mid.x; xr[dh][2] = mid.y;
                xr[dh][3] = mid.z; xr[dh][4] = mid.w;
                xr[dh][0] = (w0 > 0)      ? rowp[w0 - 1] : 0.0f;
                xr[dh][5] = (w0 + 4 < WW) ? rowp[w0 + 4] : 0.0f;
            } else {
                #pragma unroll
                for (int j = 0; j < 6; ++j) xr[dh][j] = 0.0f;
            }
        }
        // 2 channels x 4 pixels from the staged 3x6 window
        #pragma unroll
        for (int q = 0; q < 2; ++q) {
            #pragma unroll
            for (int p = 0; p < 4; ++p) {
                float t[3];
                #pragma unroll
                for (int dh = 0; dh < 3; ++dh) {
                    const float v0 = xr[dh][p]     * wgt[q][c * 9 + dh * 3 + 0];
                    const float v1 = xr[dh][p + 1] * wgt[q][c * 9 + dh * 3 + 1];
                    const float v2 = xr[dh][p + 2] * wgt[q][c * 9 + dh * 3 + 2];
                    t[dh] = f3(v0, v1, v2);
                }
                u[c][q][p] = f3(t[0], t[1], t[2]);
            }
        }
    }

    #pragma unroll
    for (int q = 0; q < 2; ++q) {
        const float bq = bias[o0 + q];
        float4 r;
        r.x = f3(u[0][q][0], u[1][q][0], u[2][q][0]) + bq;
        r.y = f3(u[0][q][1], u[1][q][1], u[2][q][1]) + bq;
        r.z = f3(u[0][q][2], u[1][q][2], u[2][q][2]) + bq;
        r.w = f3(u[0][q][3], u[1][q][3], u[2][q][3]) + bq;
        *reinterpret_cast<float4*>(out + (((size_t)(n * OO + (o0 + q)) * HH + h) * WW + w0)) = r;
    }
}

extern "C" void kernel_launch(void* const* d_in, const int* in_sizes, int n_in,
                              void* d_out, int out_size, void* d_ws, size_t ws_size,
                              hipStream_t stream) {
    const float* x    = (const float*)d_in[0];
    const float* wt   = (const float*)d_in[1];
    const float* bias = (const float*)d_in[2];
    float* out        = (float*)d_out;

    dim3 grid(HH / 16, OO / 2, NN);   // 4 x 32 x 8 = 1024 blocks, 256 thr
    sconv2d_kernel<<<grid, 256, 0, stream>>>(x, wt, bias, out);
}